// Round 7
// baseline (159.695 us; speedup 1.0000x reference)
//
#include <hip/hip_runtime.h>

// FullFixedTimeCausalConstructiveAttention — MFMA flash, paired q-tiles, swapped QK^T,
// in-register P (sigma), O^T layout, K-TILE = 128 rows (iterations halved).
// B=8, L=1024, H=8, E=64, HIST=512. Inputs fp32, output fp32.
// Layout: (b, l, h, e) row-major; per-(b,h) row stride = H*E = 512 floats.
//
// R6 (resubmitted R7: previous round was an infra failure, kernel never ran):
// evidence says duration ~= max_iterations x T_fixed (barrier+drain dominated:
// R2/R4/R5 all ~6.8-7.5K cyc/iter despite 2x DS-op changes). So: halve iterations.
//  - K-tile 128: critical block 8 iterations (was 16). Pair balance stays exact:
//    units/block = ((qtA>>1)+1) + ((qtB>>1)+1) = 9 for all a.
//  - sigma extends to 8 S-blocks: rk2[nb] = rkB[nb&1] + (nb>>1)*32; owned P pairs
//    fill 4 PV B-fragments (k = 32c+8lq+j) with zero cross-lane traffic.
//  - Vt row = 128 s (VSTR=136), XOR-chunk swizzle over 16 chunks: enumerated
//    8-lanes-per-bank-group on all LDS reads/writes (optimal for b128/b64).
#define LL   1024
#define HH   8
#define EE   64
#define KSTR 72    // Ks row stride (f16): 144 B
#define VSTR 136   // Vt row stride (f16): 272 B

#define SCALE2 0.18033688011112043f   // (1/sqrt(64)) * log2(e)

typedef _Float16 f16;
typedef _Float16 v8h  __attribute__((ext_vector_type(8)));
typedef _Float16 h2   __attribute__((ext_vector_type(2)));
typedef _Float16 h4   __attribute__((ext_vector_type(4)));
typedef float    v4f  __attribute__((ext_vector_type(4)));
typedef int      v2i  __attribute__((ext_vector_type(2)));

union U8 { v8h v; h2 h[4]; };

__device__ __forceinline__ float fexp2(float x) {
#if __has_builtin(__builtin_amdgcn_exp2f)
  return __builtin_amdgcn_exp2f(x);
#else
  return __expf(x * 0.6931471805599453f);
#endif
}

__device__ __forceinline__ h2 pkh2(float a, float b) {
#if __has_builtin(__builtin_amdgcn_cvt_pkrtz)
  return __builtin_bit_cast(h2, __builtin_amdgcn_cvt_pkrtz(a, b));
#else
  h2 r; r[0] = (f16)a; r[1] = (f16)b; return r;
#endif
}

// Reduce across the 4 lane-quarters (lanes ln, ln+16, ln+32, ln+48).
__device__ __forceinline__ float red4max(float x) {
#if __has_builtin(__builtin_amdgcn_permlane16_swap) && __has_builtin(__builtin_amdgcn_permlane32_swap)
  int xi = __float_as_int(x);
  v2i a = __builtin_amdgcn_permlane16_swap(xi, xi, false, false);
  float m = fmaxf(__int_as_float(a.x), __int_as_float(a.y));
  int mi = __float_as_int(m);
  v2i b = __builtin_amdgcn_permlane32_swap(mi, mi, false, false);
  return fmaxf(__int_as_float(b.x), __int_as_float(b.y));
#else
  x = fmaxf(x, __shfl_xor(x, 16));
  return fmaxf(x, __shfl_xor(x, 32));
#endif
}

__device__ __forceinline__ float red4sum(float x) {
#if __has_builtin(__builtin_amdgcn_permlane16_swap) && __has_builtin(__builtin_amdgcn_permlane32_swap)
  int xi = __float_as_int(x);
  v2i a = __builtin_amdgcn_permlane16_swap(xi, xi, false, false);
  float s = __int_as_float(a.x) + __int_as_float(a.y);
  int si = __float_as_int(s);
  v2i b = __builtin_amdgcn_permlane32_swap(si, si, false, false);
  return __int_as_float(b.x) + __int_as_float(b.y);
#else
  x += __shfl_xor(x, 16);
  return x + __shfl_xor(x, 32);
#endif
}

__device__ __forceinline__ void load16f(const float* __restrict__ p, float* __restrict__ f) {
  const float4* p4 = reinterpret_cast<const float4*>(p);
  float4 a = p4[0], b = p4[1], c = p4[2], d = p4[3];
  f[0]=a.x;  f[1]=a.y;  f[2]=a.z;  f[3]=a.w;
  f[4]=b.x;  f[5]=b.y;  f[6]=b.z;  f[7]=b.w;
  f[8]=c.x;  f[9]=c.y;  f[10]=c.z; f[11]=c.w;
  f[12]=d.x; f[13]=d.y; f[14]=d.z; f[15]=d.w;
}

__device__ __forceinline__ void load8f(const float* __restrict__ p, float* __restrict__ f) {
  const float4* p4 = reinterpret_cast<const float4*>(p);
  float4 a = p4[0], b = p4[1];
  f[0]=a.x; f[1]=a.y; f[2]=a.z; f[3]=a.w;
  f[4]=b.x; f[5]=b.y; f[6]=b.z; f[7]=b.w;
}

struct TileState {
  v4f   o[4];      // O^T: lane holds O[d=16nb+4lq+r][q = tile_base + w*16 + ln]
  float m, l, pd;  // per-lane stats for this tile's q-row
};

// Softmax + P-fragment pack over 8 S-blocks (128 columns).
// Lane (ln,lq) holds z[q=w*16+ln][s = kbB[nb&1] + (nb>>1)*32 + r].
__device__ __forceinline__ void softmax_pack8(
    TileState& st, const v4f* __restrict__ S, bool dt, bool drawn, float zdq,
    int qrel, const int* __restrict__ kbB, int lq, U8* __restrict__ P)
{
  float z[8][4];
#pragma unroll
  for (int nb = 0; nb < 8; ++nb)
#pragma unroll
    for (int r = 0; r < 4; ++r) z[nb][r] = S[nb][r] * SCALE2;

  if (dt) {
#pragma unroll
    for (int nb = 0; nb < 8; ++nb) {
      const int kl0 = kbB[nb & 1] + (nb >> 1) * 32;
#pragma unroll
      for (int r = 0; r < 4; ++r) {
        const int kl = kl0 + r;
        if (kl > qrel)                 z[nb][r] = -1e30f;  // causal mask
        else if (drawn && kl == qrel)  z[nb][r] = zdq;     // diag replace
      }
    }
  }

  float mloc = z[0][0];
#pragma unroll
  for (int nb = 0; nb < 8; ++nb) {
    float a01 = fmaxf(z[nb][0], z[nb][1]);
    float a23 = fmaxf(z[nb][2], z[nb][3]);
    mloc = fmaxf(mloc, fmaxf(a01, a23));
  }
  const float mx = red4max(mloc);

  const float mn = fmaxf(st.m, mx);
  const float al = fexp2(st.m - mn);
  st.m = mn;

  float p[8][4], rsum = 0.f, pdl = 0.f;
#pragma unroll
  for (int nb = 0; nb < 8; ++nb) {
    const int kl0 = kbB[nb & 1] + (nb >> 1) * 32;
#pragma unroll
    for (int r = 0; r < 4; ++r) {
      const float pv = fexp2(z[nb][r] - mn);
      p[nb][r] = pv;
      rsum += pv;
      if (dt && drawn && (kl0 + r) == qrel) pdl = pv;
    }
  }
  rsum = red4sum(rsum);
  if (dt && drawn) st.pd = red4sum(pdl);   // diag tile is last: no later rescale
  st.l = st.l * al + rsum;
#pragma unroll
  for (int nb = 0; nb < 4; ++nb)
#pragma unroll
    for (int r = 0; r < 4; ++r) st.o[nb][r] *= al;   // per-lane scalar rescale

  // P -> 4 PV B-fragments in-register (sigma: owned pairs == needed k-layout)
  h2 wq[8][2];
#pragma unroll
  for (int nb = 0; nb < 8; ++nb) {
    wq[nb][0] = pkh2(p[nb][0], p[nb][1]);
    wq[nb][1] = pkh2(p[nb][2], p[nb][3]);
  }
  const bool swp = (lq & 1);
#pragma unroll
  for (int c = 0; c < 4; ++c) {
    P[c].h[0] = swp ? wq[2 * c + 1][0] : wq[2 * c][0];
    P[c].h[1] = swp ? wq[2 * c + 1][1] : wq[2 * c][1];
    P[c].h[2] = swp ? wq[2 * c][0] : wq[2 * c + 1][0];
    P[c].h[3] = swp ? wq[2 * c][1] : wq[2 * c + 1][1];
  }
}

extern "C" __global__ __launch_bounds__(256, 2)
void ftcca_k128(const float* __restrict__ Q,  const float* __restrict__ K,
                const float* __restrict__ V,  const float* __restrict__ Qd,
                const float* __restrict__ Kd, const float* __restrict__ Vd,
                float* __restrict__ out)
{
  __shared__ f16   Ks[128 * KSTR];      // 128 K rows (f16)
  __shared__ f16   Vt[64 * VSTR];       // V transposed [d][s=128], s-chunks XOR-swizzled
  __shared__ float zdiag[64];           // diag replacement scores for tile A (log2 units)

  // bh = blockIdx & 63: the 8 pair-blocks of one (b,h) land on one XCD (L2 share)
  const int bh  = blockIdx.x & 63;
  const int a   = blockIdx.x >> 6;      // 0..7
  const int qtA = 15 - a;               // >= 8 -> all rows drawn
  const int qtB = a;                    // <= 7 -> no rows drawn
  const int b   = bh >> 3, h = bh & 7;
  const int t   = threadIdx.x;
  const int w    = t >> 6;
  const int lane = t & 63;
  const int ln   = lane & 15;
  const int lq   = lane >> 4;
  const int rs   = t >> 2;              // K staging row 0..63 (+64 for second half)
  const int es0  = (t & 3) * 16;        // K staging dim offset
  const int vr0  = (t >> 3) * 4;        // V staging rows vr0..vr0+3 (0..124)
  const int vd0  = (t & 7) * 8;         // V staging dim offset

  const size_t base = ((size_t)b * LL * HH + h) * EE;
  const int ROWF = HH * EE;             // 512

  // sigma tables (base pattern within a 32-col block)
  const int q2 = ln >> 2;
  int rkB[2], kbB[2];
  rkB[0] = ln + ((q2 + 1) >> 1) * 8;    // off {0,8,8,16}
  rkB[1] = ln + 4 + (q2 >> 1) * 8;      // off {4,4,12,12}
  kbB[0] = 4 * lq + ((lq + 1) >> 1) * 8;
  kbB[1] = 4 * lq + 4 + (lq >> 1) * 8;

  // ---- zdiag for tile A: z[l][l] = SCALE2 * (Qd[l] . Kd[l]) ----
  {
    const int l = qtA * 64 + rs;
    const float* qrow = Qd + base + (size_t)l * ROWF + es0;
    const float* krow = Kd + base + (size_t)l * ROWF + es0;
    float par = 0.f;
#pragma unroll
    for (int i = 0; i < 16; ++i) par += qrow[i] * krow[i];
    par += __shfl_xor(par, 1);
    par += __shfl_xor(par, 2);
    if ((t & 3) == 0) zdiag[rs] = SCALE2 * par;
  }

  // ---- Q fragments for both tiles (free-dim=ln, k=32c+8lq+j) ----
  const int rowt_q = w * 16 + ln;
  v8h qfA[2], qfB[2];
  {
    const float* pa = Qd + base + (size_t)(qtA * 64 + rowt_q) * ROWF;
    const float* pb = Q  + base + (size_t)(qtB * 64 + rowt_q) * ROWF;
#pragma unroll
    for (int c = 0; c < 2; ++c) {
      const float* xa = pa + 32 * c + 8 * lq;
      const float* xb = pb + 32 * c + 8 * lq;
#pragma unroll
      for (int j = 0; j < 8; ++j) { qfA[c][j] = (f16)xa[j]; qfB[c][j] = (f16)xb[j]; }
    }
  }

  TileState stA, stB;
#pragma unroll
  for (int nb = 0; nb < 4; ++nb) { stA.o[nb] = (v4f){0,0,0,0}; stB.o[nb] = (v4f){0,0,0,0}; }
  stA.m = -1e30f; stA.l = 0.f; stA.pd = 0.f;
  stB.m = -1e30f; stB.l = 0.f; stB.pd = 0.f;

  const int qlocal = w * 16 + ln;
  const int itersA = (qtA >> 1) + 1;            // 5..8 (critical: 8)
  const int dIA    = qtA >> 1;
  const int dIB    = qtB >> 1;
  const int qrelA  = ((qtA & 1) << 6) + qlocal; // q row within diag 128-tile
  const int qrelB  = ((qtB & 1) << 6) + qlocal;

  // ---- prefetch 128-row tile 0 into registers ----
  float tk[32], tv[32];
  load16f(K + base + (size_t)rs * ROWF + es0, tk);
  load16f(K + base + (size_t)(rs + 64) * ROWF + es0, tk + 16);
#pragma unroll
  for (int j = 0; j < 4; ++j)
    load8f(V + base + (size_t)(vr0 + j) * ROWF + vd0, tv + 8 * j);

  for (int i = 0; i < itersA; ++i) {
    __syncthreads();   // previous tile's LDS fully consumed
    {
      // commit register-staged 128-row tile to LDS (f16)
#pragma unroll
      for (int half = 0; half < 2; ++half) {
        v8h k0, k1;
#pragma unroll
        for (int j = 0; j < 8; ++j) { k0[j] = (f16)tk[16 * half + j]; k1[j] = (f16)tk[16 * half + 8 + j]; }
        v8h* kd0 = reinterpret_cast<v8h*>(&Ks[(rs + 64 * half) * KSTR + es0]);
        kd0[0] = k0;
        kd0[1] = k1;
      }
      // V transposed: (s=vr0+j, d) -> Vt[d*VSTR + ch*8 + (s&7)], ch = (s>>3)^(d>>3)
      const int vswz = vr0 >> 3;
#pragma unroll
      for (int dd = 0; dd < 8; ++dd) {
        const int d  = vd0 + dd;
        const int ch = vswz ^ (d >> 3);
        h4 val;
        val[0] = (f16)tv[dd];      val[1] = (f16)tv[8 + dd];
        val[2] = (f16)tv[16 + dd]; val[3] = (f16)tv[24 + dd];
        *reinterpret_cast<h4*>(&Vt[d * VSTR + ch * 8 + (vr0 & 7)]) = val;
      }
    }
    __syncthreads();

    // issue next tile's global loads; they fly under this tile's compute
    if (i < itersA - 1) {
      const size_t r0 = (size_t)((i + 1) * 128);
      load16f(K + base + (r0 + rs) * ROWF + es0, tk);
      load16f(K + base + (r0 + rs + 64) * ROWF + es0, tk + 16);
#pragma unroll
      for (int j = 0; j < 4; ++j)
        load8f(V + base + (r0 + vr0 + j) * ROWF + vd0, tv + 8 * j);
    }

    const bool doB = (i <= dIB);
    const bool dtA = (i == dIA);
    const bool dtB = (i == dIB);

    // ---- QK^T: 8 S-blocks, K fragments read ONCE, feed both chains ----
    v4f SA[8], SB[8];
#pragma unroll
    for (int nb = 0; nb < 8; ++nb) {
      const int row = rkB[nb & 1] + (nb >> 1) * 32;
      const f16* krow = &Ks[row * KSTR + 8 * lq];
      v8h k0 = *reinterpret_cast<const v8h*>(krow);
      v8h k1 = *reinterpret_cast<const v8h*>(krow + 32);
      v4f acc = (v4f){0.f, 0.f, 0.f, 0.f};
      acc = __builtin_amdgcn_mfma_f32_16x16x32_f16(k0, qfA[0], acc, 0, 0, 0);
      acc = __builtin_amdgcn_mfma_f32_16x16x32_f16(k1, qfA[1], acc, 0, 0, 0);
      SA[nb] = acc;
      if (doB) {
        v4f accb = (v4f){0.f, 0.f, 0.f, 0.f};
        accb = __builtin_amdgcn_mfma_f32_16x16x32_f16(k0, qfB[0], accb, 0, 0, 0);
        accb = __builtin_amdgcn_mfma_f32_16x16x32_f16(k1, qfB[1], accb, 0, 0, 0);
        SB[nb] = accb;
      }
    }

    // ---- two independent softmax chains ----
    U8 PA[4], PB[4];
    const float zdq = dtA ? zdiag[qlocal] : 0.f;
    softmax_pack8(stA, SA, dtA, true,  zdq, qrelA, kbB, lq, PA);
    if (doB)
      softmax_pack8(stB, SB, dtB, false, 0.f, qrelB, kbB, lq, PB);

    // ---- PV: V fragments read ONCE, 4 MFMAs per output block (K=128) ----
#pragma unroll
    for (int nb = 0; nb < 4; ++nb) {
      const int d    = nb * 16 + ln;
      const int dxor = d >> 3;
      const f16* vbase = &Vt[d * VSTR];
      v8h vf[4];
#pragma unroll
      for (int c = 0; c < 4; ++c) {
        const int ch = (4 * c + lq) ^ dxor;
        vf[c] = *reinterpret_cast<const v8h*>(vbase + ch * 8);
      }
#pragma unroll
      for (int c = 0; c < 4; ++c)
        stA.o[nb] = __builtin_amdgcn_mfma_f32_16x16x32_f16(vf[c], PA[c].v, stA.o[nb], 0, 0, 0);
      if (doB) {
#pragma unroll
        for (int c = 0; c < 4; ++c)
          stB.o[nb] = __builtin_amdgcn_mfma_f32_16x16x32_f16(vf[c], PB[c].v, stB.o[nb], 0, 0, 0);
      }
    }
  }

  // ---- epilogue: O^T stores — per-lane scalars, float4 per nb ----
  {
    const float inv = 1.f / stA.l;
    const float pdinv = stA.pd * inv;
    const int lrow = qtA * 64 + w * 16 + ln;
#pragma unroll
    for (int nb = 0; nb < 4; ++nb) {
      const int d0 = nb * 16 + lq * 4;
      const size_t g = base + (size_t)lrow * ROWF + d0;
      float4 vd4 = *reinterpret_cast<const float4*>(Vd + g);
      float4 v4  = *reinterpret_cast<const float4*>(V + g);
      float4 o4;
      o4.x = stA.o[nb][0] * inv + pdinv * (vd4.x - v4.x);
      o4.y = stA.o[nb][1] * inv + pdinv * (vd4.y - v4.y);
      o4.z = stA.o[nb][2] * inv + pdinv * (vd4.z - v4.z);
      o4.w = stA.o[nb][3] * inv + pdinv * (vd4.w - v4.w);
      *reinterpret_cast<float4*>(out + g) = o4;
    }
  }
  {
    const float inv = 1.f / stB.l;
    const int lrow = qtB * 64 + w * 16 + ln;
#pragma unroll
    for (int nb = 0; nb < 4; ++nb) {
      const int d0 = nb * 16 + lq * 4;
      const size_t g = base + (size_t)lrow * ROWF + d0;
      float4 o4;
      o4.x = stB.o[nb][0] * inv;
      o4.y = stB.o[nb][1] * inv;
      o4.z = stB.o[nb][2] * inv;
      o4.w = stB.o[nb][3] * inv;
      *reinterpret_cast<float4*>(out + g) = o4;
    }
  }
}

extern "C" void kernel_launch(void* const* d_in, const int* in_sizes, int n_in,
                              void* d_out, int out_size, void* d_ws, size_t ws_size,
                              hipStream_t stream) {
  const float* q  = (const float*)d_in[0];
  const float* k  = (const float*)d_in[1];
  const float* v  = (const float*)d_in[2];
  const float* qd = (const float*)d_in[3];
  const float* kd = (const float*)d_in[4];
  const float* vd = (const float*)d_in[5];
  // d_in[6] = attn_mask (analytic), d_in[7] = history_len (HIST)
  float* out = (float*)d_out;

  // 512 blocks: 64 (b,h) x 8 pairs — uniform 9 tile-units per block
  ftcca_k128<<<dim3(512), dim3(256), 0, stream>>>(q, k, v, qd, kd, vd, out);
}

// Round 8
// 157.493 us; speedup vs baseline: 1.0140x; 1.0140x over previous
//
#include <hip/hip_runtime.h>

// FullFixedTimeCausalConstructiveAttention — MFMA flash, split blocks, swapped QK^T,
// in-register P (sigma), O^T layout, DOUBLE-BUFFERED LDS (one barrier per iter).
// B=8, L=1024, H=8, E=64, HIST=512. Inputs fp32, output fp32.
// Layout: (b, l, h, e) row-major; per-(b,h) row stride = H*E = 512 floats.
//
// R8: waves in a block are phase-locked by per-iter barriers (R7 falsified the
// barrier-count theory; stall = serial chain / too few independent streams).
// This round overlaps the staging segment with compute:
//  - Ks/Vt x2 buffers; per iter: ds_write tile i+1 -> buf^1 (drains under compute),
//    issue loads tile i+2, compute tile i from buf^0, ONE barrier.
//  - base = R4 (best so far, 44.5us): 1024 blocks, 4 blocks/CU, in-reg P, O^T.
#define LL   1024
#define HH   8
#define EE   64
#define KSTR 72   // f16 LDS row stride: 144 B = 16B-aligned

#define SCALE2 0.18033688011112043f   // (1/sqrt(64)) * log2(e)

typedef _Float16 f16;
typedef _Float16 v8h  __attribute__((ext_vector_type(8)));
typedef _Float16 h2   __attribute__((ext_vector_type(2)));
typedef float    v4f  __attribute__((ext_vector_type(4)));
typedef int      v2i  __attribute__((ext_vector_type(2)));

__device__ __forceinline__ float fexp2(float x) {
#if __has_builtin(__builtin_amdgcn_exp2f)
  return __builtin_amdgcn_exp2f(x);
#else
  return __expf(x * 0.6931471805599453f);
#endif
}

__device__ __forceinline__ h2 pkh2(float a, float b) {
#if __has_builtin(__builtin_amdgcn_cvt_pkrtz)
  return __builtin_bit_cast(h2, __builtin_amdgcn_cvt_pkrtz(a, b));
#else
  h2 r; r[0] = (f16)a; r[1] = (f16)b; return r;
#endif
}

// Reduce across the 4 lane-quarters (lanes ln, ln+16, ln+32, ln+48).
__device__ __forceinline__ float red4max(float x) {
#if __has_builtin(__builtin_amdgcn_permlane16_swap) && __has_builtin(__builtin_amdgcn_permlane32_swap)
  int xi = __float_as_int(x);
  v2i a = __builtin_amdgcn_permlane16_swap(xi, xi, false, false);
  float m = fmaxf(__int_as_float(a.x), __int_as_float(a.y));
  int mi = __float_as_int(m);
  v2i b = __builtin_amdgcn_permlane32_swap(mi, mi, false, false);
  return fmaxf(__int_as_float(b.x), __int_as_float(b.y));
#else
  x = fmaxf(x, __shfl_xor(x, 16));
  return fmaxf(x, __shfl_xor(x, 32));
#endif
}

__device__ __forceinline__ float red4sum(float x) {
#if __has_builtin(__builtin_amdgcn_permlane16_swap) && __has_builtin(__builtin_amdgcn_permlane32_swap)
  int xi = __float_as_int(x);
  v2i a = __builtin_amdgcn_permlane16_swap(xi, xi, false, false);
  float s = __int_as_float(a.x) + __int_as_float(a.y);
  int si = __float_as_int(s);
  v2i b = __builtin_amdgcn_permlane32_swap(si, si, false, false);
  return __int_as_float(b.x) + __int_as_float(b.y);
#else
  x += __shfl_xor(x, 16);
  return x + __shfl_xor(x, 32);
#endif
}

__device__ __forceinline__ void load16f(const float* __restrict__ p, float* __restrict__ f) {
  const float4* p4 = reinterpret_cast<const float4*>(p);
  float4 a = p4[0], b = p4[1], c = p4[2], d = p4[3];
  f[0]=a.x;  f[1]=a.y;  f[2]=a.z;  f[3]=a.w;
  f[4]=b.x;  f[5]=b.y;  f[6]=b.z;  f[7]=b.w;
  f[8]=c.x;  f[9]=c.y;  f[10]=c.z; f[11]=c.w;
  f[12]=d.x; f[13]=d.y; f[14]=d.z; f[15]=d.w;
}

__device__ __forceinline__ void load8f(const float* __restrict__ p, float* __restrict__ f) {
  const float4* p4 = reinterpret_cast<const float4*>(p);
  float4 a = p4[0], b = p4[1];
  f[0]=a.x; f[1]=a.y; f[2]=a.z; f[3]=a.w;
  f[4]=b.x; f[5]=b.y; f[6]=b.z; f[7]=b.w;
}

struct TileState {
  v4f   o[4];      // O^T: lane holds O[d=16nb+4lq+r][q = tile_base + w*16 + ln]
  float m, l, pd;  // per-lane stats for q = ln
};

// One K-tile update. Lane (ln,lq) owns z[q=w*16+ln][s=sigma(nb,4lq+r)].
__device__ __forceinline__ void tile_update(
    TileState& st, const v8h* __restrict__ qf, bool dt, bool drawn,
    const f16* __restrict__ Ks, const f16* __restrict__ Vt,
    const float* __restrict__ zd,
    int w, int ln, int lq,
    const int* __restrict__ rk, const int* __restrict__ kb)
{
  // ---- S^T = K Q^T with permuted K rows: mfma nb, A-row m=ln <- K row rk[nb] ----
  v4f S[4];
#pragma unroll
  for (int nb = 0; nb < 4; ++nb) {
    const f16* krow = &Ks[rk[nb] * KSTR + 8 * lq];
    v8h k0 = *reinterpret_cast<const v8h*>(krow);
    v8h k1 = *reinterpret_cast<const v8h*>(krow + 32);
    v4f acc = (v4f){0.f, 0.f, 0.f, 0.f};
    acc = __builtin_amdgcn_mfma_f32_16x16x32_f16(k0, qf[0], acc, 0, 0, 0);
    acc = __builtin_amdgcn_mfma_f32_16x16x32_f16(k1, qf[1], acc, 0, 0, 0);
    S[nb] = acc;
  }

  float z[4][4];
#pragma unroll
  for (int nb = 0; nb < 4; ++nb)
#pragma unroll
    for (int r = 0; r < 4; ++r) z[nb][r] = S[nb][r] * SCALE2;

  const int qlocal = w * 16 + ln;
  if (dt) {
    const float zdq = drawn ? zd[qlocal] : 0.f;
#pragma unroll
    for (int nb = 0; nb < 4; ++nb) {
#pragma unroll
      for (int r = 0; r < 4; ++r) {
        const int kl = kb[nb] + r;             // sigma(nb, 4lq+r)
        if (kl > qlocal)                 z[nb][r] = -1e30f;  // causal mask
        else if (drawn && kl == qlocal)  z[nb][r] = zdq;     // diag replace
      }
    }
  }

  // ---- online softmax: local 16-tree + 2 permlane swaps (q=ln lane-local) ----
  float a0 = fmaxf(fmaxf(z[0][0], z[0][1]), fmaxf(z[0][2], z[0][3]));
  float a1 = fmaxf(fmaxf(z[1][0], z[1][1]), fmaxf(z[1][2], z[1][3]));
  float a2 = fmaxf(fmaxf(z[2][0], z[2][1]), fmaxf(z[2][2], z[2][3]));
  float a3 = fmaxf(fmaxf(z[3][0], z[3][1]), fmaxf(z[3][2], z[3][3]));
  const float mx = red4max(fmaxf(fmaxf(a0, a1), fmaxf(a2, a3)));

  const float mn = fmaxf(st.m, mx);
  const float al = fexp2(st.m - mn);
  st.m = mn;

  float p[4][4], rsum = 0.f, pdl = 0.f;
#pragma unroll
  for (int nb = 0; nb < 4; ++nb) {
#pragma unroll
    for (int r = 0; r < 4; ++r) {
      const float pv = fexp2(z[nb][r] - mn);
      p[nb][r] = pv;
      rsum += pv;
      if (dt && drawn && (kb[nb] + r) == qlocal) pdl = pv;
    }
  }
  rsum = red4sum(rsum);
  if (dt && drawn) st.pd = red4sum(pdl);   // diag tile is last: no later rescale
  st.l = st.l * al + rsum;
#pragma unroll
  for (int nb = 0; nb < 4; ++nb)
#pragma unroll
    for (int r = 0; r < 4; ++r) st.o[nb][r] *= al;   // per-lane scalar rescale

  // ---- P -> B-fragment in-register: owned pairs == needed k-layout by sigma ----
  h2 wq[4][2];
#pragma unroll
  for (int nb = 0; nb < 4; ++nb) {
    wq[nb][0] = pkh2(p[nb][0], p[nb][1]);
    wq[nb][1] = pkh2(p[nb][2], p[nb][3]);
  }
  const bool swp = (lq & 1);
  union U8 { v8h v; h2 h[4]; } A0, A1;
  A0.h[0] = swp ? wq[1][0] : wq[0][0];
  A0.h[1] = swp ? wq[1][1] : wq[0][1];
  A0.h[2] = swp ? wq[0][0] : wq[1][0];
  A0.h[3] = swp ? wq[0][1] : wq[1][1];
  A1.h[0] = swp ? wq[3][0] : wq[2][0];
  A1.h[1] = swp ? wq[3][1] : wq[2][1];
  A1.h[2] = swp ? wq[2][0] : wq[3][0];
  A1.h[3] = swp ? wq[2][1] : wq[3][1];

  // ---- O^T += V^T P^T: A = V-frag (d=16nb+ln), B = P-frag ----
#pragma unroll
  for (int nb = 0; nb < 4; ++nb) {
    const int d   = nb * 16 + ln;
    const int dsw = (d >> 3) & 7;
    const f16* vbase = &Vt[d * KSTR];
    v8h v0 = *reinterpret_cast<const v8h*>(vbase + (((lq    ) ^ dsw) & 7) * 8);
    v8h v1 = *reinterpret_cast<const v8h*>(vbase + (((lq + 4) ^ dsw) & 7) * 8);
    st.o[nb] = __builtin_amdgcn_mfma_f32_16x16x32_f16(v0, A0.v, st.o[nb], 0, 0, 0);
    st.o[nb] = __builtin_amdgcn_mfma_f32_16x16x32_f16(v1, A1.v, st.o[nb], 0, 0, 0);
  }
}

extern "C" __global__ __launch_bounds__(256, 4)
void ftcca_dbuf(const float* __restrict__ Q,  const float* __restrict__ K,
                const float* __restrict__ V,  const float* __restrict__ Qd,
                const float* __restrict__ Kd, const float* __restrict__ Vd,
                float* __restrict__ out)
{
  __shared__ f16   Ks[2][64 * KSTR];    // double-buffered K tiles (f16)
  __shared__ f16   Vt[2][64 * KSTR];    // double-buffered V^T tiles, XOR-chunk swizzled
  __shared__ float zdiag[64];           // diag replacement scores (log2 units)

  // bh = blockIdx & 63: all 16 q-tile blocks of one (b,h) land on one XCD -> K/V L2 reuse
  const int bh  = blockIdx.x & 63;
  const int a   = blockIdx.x >> 6;      // 0..15
  const int qt  = 15 - a;               // big K-ranges first
  const bool drawn = (qt >= 8);         // l >= 512 -> drawn rows
  const int b   = bh >> 3, h = bh & 7;
  const int t   = threadIdx.x;
  const int w    = t >> 6;
  const int lane = t & 63;
  const int ln   = lane & 15;
  const int lq   = lane >> 4;
  const int rs   = t >> 2;              // K staging row 0..63
  const int es0  = (t & 3) * 16;        // K staging dim offset
  const int vr0  = (t >> 3) * 2;        // V staging row pair 0..62
  const int vd0  = (t & 7) * 8;         // V staging dim offset

  const size_t base = ((size_t)b * LL * HH + h) * EE;
  const int ROWF = HH * EE;             // 512

  // sigma tables: K-frag read rows (indexed by ln) and owned-k bases (indexed by lq)
  const int q2 = ln >> 2;
  int rk[4], kb[4];
  rk[0] = ln + ((q2 + 1) >> 1) * 8;     // off[0] = {0,8,8,16}
  rk[1] = ln + 4 + (q2 >> 1) * 8;       // off[1] = {4,4,12,12}
  rk[2] = rk[0] + 32;
  rk[3] = rk[1] + 32;
  kb[0] = 4 * lq + ((lq + 1) >> 1) * 8;
  kb[1] = 4 * lq + 4 + (lq >> 1) * 8;
  kb[2] = kb[0] + 32;
  kb[3] = kb[1] + 32;

  // ---- zdiag (drawn tiles only): z[l][l] = SCALE2 * (Qd[l] . Kd[l]) ----
  if (drawn) {
    const int l = qt * 64 + rs;
    const float* qrow = Qd + base + (size_t)l * ROWF + es0;
    const float* krow = Kd + base + (size_t)l * ROWF + es0;
    float par = 0.f;
#pragma unroll
    for (int i = 0; i < 16; ++i) par += qrow[i] * krow[i];
    par += __shfl_xor(par, 1);
    par += __shfl_xor(par, 2);
    if ((t & 3) == 0) zdiag[rs] = SCALE2 * par;
  }

  // ---- Q fragments (B-operand of QK^T: free-dim=ln, k=32c+8lq+j) ----
  const int rowt_q = w * 16 + ln;
  const float* qsrc = drawn ? Qd : Q;
  v8h qf[2];
  {
    const float* pq = qsrc + base + (size_t)(qt * 64 + rowt_q) * ROWF;
#pragma unroll
    for (int c = 0; c < 2; ++c) {
      const float* x = pq + 32 * c + 8 * lq;
#pragma unroll
      for (int j = 0; j < 8; ++j) qf[c][j] = (f16)x[j];
    }
  }

  TileState st;
#pragma unroll
  for (int nb = 0; nb < 4; ++nb) st.o[nb] = (v4f){0, 0, 0, 0};
  st.m = -1e30f; st.l = 0.f; st.pd = 0.f;

  const int iters = qt + 1;
  const int vswz = vr0 >> 3;

  // ---- prologue: stage tile 0 into buf0; issue loads for tile 1 ----
  float tk[16], tv[16];
  load16f(K + base + (size_t)rs * ROWF + es0, tk);
  load8f(V + base + (size_t)vr0 * ROWF + vd0, tv);
  load8f(V + base + (size_t)(vr0 + 1) * ROWF + vd0, tv + 8);
  {
    v8h k0, k1;
#pragma unroll
    for (int j = 0; j < 8; ++j) { k0[j] = (f16)tk[j]; k1[j] = (f16)tk[8 + j]; }
    v8h* kd0 = reinterpret_cast<v8h*>(&Ks[0][rs * KSTR + es0]);
    kd0[0] = k0;
    kd0[1] = k1;
#pragma unroll
    for (int dd = 0; dd < 8; ++dd) {
      const int d  = vd0 + dd;
      const int ch = (vswz ^ (d >> 3)) & 7;
      h2 val; val[0] = (f16)tv[dd]; val[1] = (f16)tv[8 + dd];
      *reinterpret_cast<h2*>(&Vt[0][d * KSTR + ch * 8 + (vr0 & 7)]) = val;
    }
  }
  if (iters > 1) {
    const size_t r0 = 64;
    load16f(K + base + (r0 + rs) * ROWF + es0, tk);
    load8f(V + base + (r0 + vr0) * ROWF + vd0, tv);
    load8f(V + base + (r0 + vr0 + 1) * ROWF + vd0, tv + 8);
  }
  __syncthreads();

  // ---- main loop: ONE barrier per iteration ----
  // iter i: ds_write tile i+1 -> buf[(i+1)&1] (drains under compute),
  //         issue loads tile i+2, compute tile i from buf[i&1], barrier.
  // Hazard audit: reads of buf[(i+1)&1] were iter i-1's compute, before the
  // end-of-(i-1) barrier; writes here are after it. Reads of buf[i&1] (this
  // iter) vs writes in iter i+1: separated by end-of-i barrier.
  for (int i = 0; i < iters; ++i) {
    if (i + 1 < iters) {
      f16* Kw = Ks[(i + 1) & 1];
      f16* Vw = Vt[(i + 1) & 1];
      v8h k0, k1;
#pragma unroll
      for (int j = 0; j < 8; ++j) { k0[j] = (f16)tk[j]; k1[j] = (f16)tk[8 + j]; }
      v8h* kd0 = reinterpret_cast<v8h*>(&Kw[rs * KSTR + es0]);
      kd0[0] = k0;
      kd0[1] = k1;
#pragma unroll
      for (int dd = 0; dd < 8; ++dd) {
        const int d  = vd0 + dd;
        const int ch = (vswz ^ (d >> 3)) & 7;
        h2 val; val[0] = (f16)tv[dd]; val[1] = (f16)tv[8 + dd];
        *reinterpret_cast<h2*>(&Vw[d * KSTR + ch * 8 + (vr0 & 7)]) = val;
      }
      if (i + 2 < iters) {
        const size_t r0 = (size_t)((i + 2) * 64);
        load16f(K + base + (r0 + rs) * ROWF + es0, tk);
        load8f(V + base + (r0 + vr0) * ROWF + vd0, tv);
        load8f(V + base + (r0 + vr0 + 1) * ROWF + vd0, tv + 8);
      }
    }

    tile_update(st, qf, i == qt, drawn, Ks[i & 1], Vt[i & 1], zdiag, w, ln, lq, rk, kb);
    __syncthreads();
  }

  // ---- epilogue: O^T store — per-lane scalars, float4 per nb ----
  const float inv = 1.f / st.l;
  const float pdinv = st.pd * inv;
  const int lrow = qt * 64 + w * 16 + ln;

#pragma unroll
  for (int nb = 0; nb < 4; ++nb) {
    const int d0 = nb * 16 + lq * 4;
    const size_t g = base + (size_t)lrow * ROWF + d0;
    float4 o4;
    o4.x = st.o[nb][0] * inv;
    o4.y = st.o[nb][1] * inv;
    o4.z = st.o[nb][2] * inv;
    o4.w = st.o[nb][3] * inv;
    if (drawn) {
      float4 vd4 = *reinterpret_cast<const float4*>(Vd + g);
      float4 v4  = *reinterpret_cast<const float4*>(V + g);
      o4.x += pdinv * (vd4.x - v4.x);
      o4.y += pdinv * (vd4.y - v4.y);
      o4.z += pdinv * (vd4.z - v4.z);
      o4.w += pdinv * (vd4.w - v4.w);
    }
    *reinterpret_cast<float4*>(out + g) = o4;
  }
}

extern "C" void kernel_launch(void* const* d_in, const int* in_sizes, int n_in,
                              void* d_out, int out_size, void* d_ws, size_t ws_size,
                              hipStream_t stream) {
  const float* q  = (const float*)d_in[0];
  const float* k  = (const float*)d_in[1];
  const float* v  = (const float*)d_in[2];
  const float* qd = (const float*)d_in[3];
  const float* kd = (const float*)d_in[4];
  const float* vd = (const float*)d_in[5];
  // d_in[6] = attn_mask (analytic), d_in[7] = history_len (HIST)
  float* out = (float*)d_out;

  // 1024 blocks: 64 (b,h) x 16 q-tiles — 4 blocks/CU resident, big K-ranges first
  ftcca_dbuf<<<dim3(1024), dim3(256), 0, stream>>>(q, k, v, qd, kd, vd, out);
}